// Round 12
// baseline (366.037 us; speedup 1.0000x reference)
//
#include <hip/hip_runtime.h>
#include <stdint.h>

// ---------------------------------------------------------------------------
// RoIHead: out = crop_and_resize(feature, rois) @ (W_fc @ [W_loc|W_score])
//                + (b_fc @ [W_loc|W_score] + [b_loc|b_score])
// R12: FILL-SHAPED gemm1 read stream. 10 failed micro-theories all shared one
// property: 16KB-strided row-window reads (forced by 64-row MFMA tiles).
// Now block = 16 rows x full K = one 256KB CONTIGUOUS slab, staged with
// lane-dense 4KB instructions marching linearly (byte-identical to the
// 6.8 TB/s fill pattern). K in two 64KB LDS halves; h1 staging pipelined
// inside h0's MFMA loop; B-frags from L2 regs (depth 4). Full K per block ->
// direct bf16 WcT write (addcvt/Pg1 deleted). No asm, no manual waitcnt.
// ---------------------------------------------------------------------------

typedef float          f32x4 __attribute__((ext_vector_type(4)));
typedef __bf16         bfx8  __attribute__((ext_vector_type(8)));
typedef __bf16         bfx4  __attribute__((ext_vector_type(4)));
typedef __bf16         bfx2  __attribute__((ext_vector_type(2)));

#define KBIG 25088   // 7*7*512
#define NMID 4096    // FC_OUT
#define NROIS 2000
#define G1BLOCKS 1568 // 25088/16 rows per block
#define SPLITS 28    // gemm2 K-splits

__device__ __forceinline__ void gll16(const void* g, void* l) {
  __builtin_amdgcn_global_load_lds(
      (const __attribute__((address_space(1))) void*)(uintptr_t)(g),
      (__attribute__((address_space(3))) void*)(uintptr_t)(l), 16, 0, 0);
}

// ---------------------------------------------------------------------------
// prep: blocks 0..2047 build WcatT[128][4096] bf16; 2048..2175 compute bc.
// ---------------------------------------------------------------------------
__global__ __launch_bounds__(256) void k_prep(const float* __restrict__ Wl,
                                              const float* __restrict__ Ws,
                                              const float* __restrict__ bfc,
                                              const float* __restrict__ bl,
                                              const float* __restrict__ bs,
                                              unsigned short* __restrict__ WcatT,
                                              float* __restrict__ bc) {
  if (blockIdx.x < 2048) {
    int idx = blockIdx.x * 256 + threadIdx.x;
    int c = idx >> 12, k = idx & 4095;
    float v = 0.0f;
    if (c < 84)       v = Wl[k * 84 + c];
    else if (c < 105) v = Ws[k * 21 + (c - 84)];
    ((__bf16*)WcatT)[idx] = (__bf16)v;
  } else {
    int c = blockIdx.x - 2048;   // 0..127
    int t = threadIdx.x;
    __shared__ float red[256];
    float p = 0.0f;
    if (c < 105) {
      for (int k = t; k < 4096; k += 256) {
        float w = (c < 84) ? Wl[k * 84 + c] : Ws[k * 21 + (c - 84)];
        p += bfc[k] * w;
      }
    }
    red[t] = p;
    __syncthreads();
    for (int s = 128; s > 0; s >>= 1) {
      if (t < s) red[t] += red[t + s];
      __syncthreads();
    }
    if (t == 0) {
      float bias = (c < 84) ? bl[c] : (c < 105 ? bs[c - 84] : 0.0f);
      bc[c] = (c < 105) ? (red[0] + bias) : 0.0f;
    }
  }
}

// ---------------------------------------------------------------------------
// GEMM1: block bx -> rows m0=bx*16 (256KB contiguous slab of W_fc), full K.
// WcT[n][m0:m0+16] bf16 = (Wfc[m0:m0+16][:] @ Wcat)^T.
// LDS sA[2 halves][16 rows][2048 bf16], XOR-swizzled (chunk ^ (row&7)).
// Stage: per row, 2 dense 4KB instrs (lane byte = t*16) -> cvt -> 2 bfx4.
// Compute: 64 kk per half; 2 MFMA/kk/wave (wave w owns n = w*32..+31).
// h1 staging pipelined inside h0's kk loop (row g at group g, store g-2).
// B: L2 reg pipeline depth 4 (bqA..bqD), all indices static.
// ---------------------------------------------------------------------------
__global__ __launch_bounds__(256) void k_gemm1(const float* __restrict__ Wfc,
                                               const unsigned short* __restrict__ WcatTu,
                                               unsigned short* __restrict__ WcTu) {
  __shared__ __align__(16) char sA[131072];   // [2][16][4096 B]
  const int t = threadIdx.x;
  const int lane = t & 63, w = t >> 6;
  const int l15 = lane & 15, l4 = lane >> 4;
  const int m0 = blockIdx.x * 16;
  const float* abase = Wfc + (size_t)m0 * NMID;
  const __bf16* Wcat = (const __bf16*)WcatTu;
  __bf16* WcT = (__bf16*)WcTu;
  f32x4 acc[2] = {};

  // dense slab load: one row, one half -> 2 f32x4 per thread (4KB instrs)
  auto rowLoad = [&](f32x4* d, int h, int r) {
    const float* src = abase + (size_t)r * NMID + h * 2048 + t * 4;
    d[0] = *(const f32x4*)(src);
    d[1] = *(const f32x4*)(src + 1024);
  };
  auto rowStore = [&](const f32x4* d, int h, int r) {
    bfx4 p0, p1;
#pragma unroll
    for (int j = 0; j < 4; ++j) { p0[j] = (__bf16)d[0][j]; p1[j] = (__bf16)d[1][j]; }
    char* rb = sA + h * 65536 + r * 4096;
    *(bfx4*)(rb + ((((t >> 1) + 0)   ^ (r & 7)) << 4) + (t & 1) * 8) = p0;
    *(bfx4*)(rb + ((((t >> 1) + 128) ^ (r & 7)) << 4) + (t & 1) * 8) = p1;
  };
  auto g4load = [&](f32x4* g, int h, int r0) {
    rowLoad(g + 0, h, r0);     rowLoad(g + 2, h, r0 + 1);
    rowLoad(g + 4, h, r0 + 2); rowLoad(g + 6, h, r0 + 3);
  };
  auto g4store = [&](const f32x4* g, int h, int r0) {
    rowStore(g + 0, h, r0);     rowStore(g + 2, h, r0 + 1);
    rowStore(g + 4, h, r0 + 2); rowStore(g + 6, h, r0 + 3);
  };
  auto bload = [&](bfx8* dst, int kg) {
    dst[0] = *(const bfx8*)(Wcat + (size_t)(w * 32 + l15) * NMID + kg + l4 * 8);
    dst[1] = *(const bfx8*)(Wcat + (size_t)(w * 32 + 16 + l15) * NMID + kg + l4 * 8);
  };
  auto mfma2 = [&](int h, int kk, const bfx8* bq) {
    const int R = l15;
    bfx8 af = *(const bfx8*)(sA + h * 65536 + R * 4096 +
                             ((((kk << 2) + l4) ^ (R & 7)) << 4));
    acc[0] = __builtin_amdgcn_mfma_f32_16x16x32_bf16(af, bq[0], acc[0], 0, 0, 0);
    acc[1] = __builtin_amdgcn_mfma_f32_16x16x32_bf16(af, bq[1], acc[1], 0, 0, 0);
  };

  f32x4 gE[8], gO[8];
  bfx8 bqA[2], bqB[2], bqC[2], bqD[2];

  // B preload for h0 kk=0..3 (L2; rides under the dense burst)
  bload(bqA, 0); bload(bqB, 32); bload(bqC, 64); bload(bqD, 96);

  // ---- stage half 0: 16 rows, 4-row pipelined (dense, fill-shaped) ----
  g4load(gE, 0, 0);
  g4load(gO, 0, 4);
  g4store(gE, 0, 0);
  g4load(gE, 0, 8);
  g4store(gO, 0, 4);
  g4load(gO, 0, 12);
  g4store(gE, 0, 8);
  g4store(gO, 0, 12);
  __syncthreads();

  // ---- compute half 0 (64 kk) + pipeline half-1 staging ----
  f32x4 r0[2], r1[2];   // two single-row banks for h1 rows
#pragma unroll
  for (int g = 0; g < 16; ++g) {
    const int kk0 = g * 4;
    // h1 staging hooks: store row g-2 (loaded 2 groups ago), load row g
    if (g >= 2) {
      if (g & 1) rowStore(r1, 1, g - 2); else rowStore(r0, 1, g - 2);
    }
    if (g & 1) rowLoad(r1, 1, g); else rowLoad(r0, 1, g);
    // 4 MFMA k-steps with depth-4 B pipeline
    mfma2(0, kk0 + 0, bqA); if (g < 15) bload(bqA, (kk0 + 4) * 32);
    mfma2(0, kk0 + 1, bqB); if (g < 15) bload(bqB, (kk0 + 5) * 32);
    mfma2(0, kk0 + 2, bqC); if (g < 15) bload(bqC, (kk0 + 6) * 32);
    mfma2(0, kk0 + 3, bqD); if (g < 15) bload(bqD, (kk0 + 7) * 32);
  }
  // finish h1 staging (rows 14,15) and preload B for h1 kk=0..3
  rowStore(r0, 1, 14);
  rowStore(r1, 1, 15);
  bload(bqA, 2048); bload(bqB, 2048 + 32); bload(bqC, 2048 + 64); bload(bqD, 2048 + 96);
  __syncthreads();

  // ---- compute half 1 (64 kk) ----
#pragma unroll
  for (int g = 0; g < 16; ++g) {
    const int kk0 = g * 4;
    mfma2(1, kk0 + 0, bqA); if (g < 15) bload(bqA, 2048 + (kk0 + 4) * 32);
    mfma2(1, kk0 + 1, bqB); if (g < 15) bload(bqB, 2048 + (kk0 + 5) * 32);
    mfma2(1, kk0 + 2, bqC); if (g < 15) bload(bqC, 2048 + (kk0 + 6) * 32);
    mfma2(1, kk0 + 3, bqD); if (g < 15) bload(bqD, 2048 + (kk0 + 7) * 32);
  }

  // epilogue: D col(l15)=n-frag, row(l4*4+i)=m -> 8B bf16 stores
#pragma unroll
  for (int ni = 0; ni < 2; ++ni) {
    const int n = w * 32 + ni * 16 + l15;
    bfx4 pk;
#pragma unroll
    for (int i = 0; i < 4; ++i) pk[i] = (__bf16)acc[ni][i];
    *(bfx4*)(WcT + (size_t)n * KBIG + m0 + l4 * 4) = pk;
  }
}

// ---------------------------------------------------------------------------
// pool: standalone, one block per roi, tf crop_and_resize -> bf16 rows.
// ---------------------------------------------------------------------------
__global__ __launch_bounds__(256) void k_pool(const float* __restrict__ F,
                                              const float* __restrict__ rois,
                                              const int* __restrict__ ihp,
                                              const int* __restrict__ iwp,
                                              unsigned short* __restrict__ A) {
  const int r = blockIdx.x;
  const int t = threadIdx.x;
  const float ih = (float)ihp[0], iw = (float)iwp[0];
  const float y1 = rois[r * 4 + 0] / ih;
  const float x1 = rois[r * 4 + 1] / iw;
  const float y2 = rois[r * 4 + 2] / ih;
  const float x2 = rois[r * 4 + 3] / iw;
  const float sy = (y2 - y1) * 49.0f / 6.0f;
  const float sx = (x2 - x1) * 49.0f / 6.0f;
  const int ch = t * 2;
  __bf16* __restrict__ Arow = (__bf16*)(A + (size_t)r * KBIG);

  auto cellcoords = [&](int cell, int& o00, int& o01, int& o10, int& o11,
                        float& yl, float& xl, bool& valid) {
    const int iy = cell / 7, ix = cell - iy * 7;
    const float in_y = y1 * 49.0f + (float)iy * sy;
    const float in_x = x1 * 49.0f + (float)ix * sx;
    const float y0f = floorf(in_y), x0f = floorf(in_x);
    yl = in_y - y0f; xl = in_x - x0f;
    const int y0  = (int)fminf(fmaxf(y0f, 0.0f), 49.0f);
    const int y1i = (int)fminf(fmaxf(y0f + 1.0f, 0.0f), 49.0f);
    const int x0  = (int)fminf(fmaxf(x0f, 0.0f), 49.0f);
    const int x1i = (int)fminf(fmaxf(x0f + 1.0f, 0.0f), 49.0f);
    valid = (in_y >= 0.0f) && (in_y <= 49.0f) && (in_x >= 0.0f) && (in_x <= 49.0f);
    o00 = (y0 * 50 + x0) * 512;  o01 = (y0 * 50 + x1i) * 512;
    o10 = (y1i * 50 + x0) * 512; o11 = (y1i * 50 + x1i) * 512;
  };

  int o00, o01, o10, o11; float yl, xl; bool valid;
  cellcoords(0, o00, o01, o10, o11, yl, xl, valid);
  float2 f00 = *(const float2*)&F[o00 + ch];
  float2 f01 = *(const float2*)&F[o01 + ch];
  float2 f10 = *(const float2*)&F[o10 + ch];
  float2 f11 = *(const float2*)&F[o11 + ch];

  for (int cell = 0; cell < 49; ++cell) {
    const float2 g00 = f00, g01 = f01, g10 = f10, g11 = f11;
    const float pyl = yl, pxl = xl;
    const bool pv = valid;
    if (cell < 48) {
      cellcoords(cell + 1, o00, o01, o10, o11, yl, xl, valid);
      f00 = *(const float2*)&F[o00 + ch];
      f01 = *(const float2*)&F[o01 + ch];
      f10 = *(const float2*)&F[o10 + ch];
      f11 = *(const float2*)&F[o11 + ch];
    }
    float oA = 0.0f, oB = 0.0f;
    if (pv) {
      float t0 = g00.x * (1.0f - pxl) + g01.x * pxl;
      float t1 = g00.y * (1.0f - pxl) + g01.y * pxl;
      float b0 = g10.x * (1.0f - pxl) + g11.x * pxl;
      float b1 = g10.y * (1.0f - pxl) + g11.y * pxl;
      oA = t0 * (1.0f - pyl) + b0 * pyl;
      oB = t1 * (1.0f - pyl) + b1 * pyl;
    }
    bfx2 v; v[0] = (__bf16)oA; v[1] = (__bf16)oB;
    *(bfx2*)(Arow + cell * 512 + ch) = v;
  }
}

// ---------------------------------------------------------------------------
// GEMM2: P[mt*28+sp][64][128] f32 = pool_tile(mt) @ WcT_slice(sp). (proven)
// ---------------------------------------------------------------------------
__global__ __launch_bounds__(256) void k_gemm2(const unsigned short* __restrict__ Ap,
                                               const unsigned short* __restrict__ WcT,
                                               float* __restrict__ P) {
  __shared__ __align__(16) char S[49152];
  const int t = threadIdx.x;
  const int lane = t & 63, wid = t >> 6;
  const int wm = wid >> 1, wn = wid & 1;
  const int l15 = lane & 15, l4 = lane >> 4;
  const int mt = blockIdx.x, sp = blockIdx.y;
  const int kbase = sp * 896;     // 14 BK-steps of 64
  const int jlog = (t & 7) ^ ((t >> 3) & 7);
  f32x4 acc[2][4] = {};

  int ar0 = mt * 64 + (t >> 3);
  int ar1 = ar0 + 32;
  if (ar0 > NROIS - 1) ar0 = NROIS - 1;
  if (ar1 > NROIS - 1) ar1 = NROIS - 1;
  const unsigned short* asrc0 = Ap + (size_t)ar0 * KBIG + jlog * 8;
  const unsigned short* asrc1 = Ap + (size_t)ar1 * KBIG + jlog * 8;

  auto stage2 = [&](int c, int off) {
    const int k0 = kbase + c * 64;
    gll16(asrc0 + k0, S + off + wid * 1024);
    gll16(asrc1 + k0, S + off + 4096 + wid * 1024);
#pragma unroll
    for (int q = 0; q < 4; ++q)
      gll16(WcT + (size_t)(q * 32 + (t >> 3)) * KBIG + k0 + jlog * 8,
            S + off + 8192 + q * 4096 + wid * 1024);
  };
  auto compute2 = [&](int off) {
#pragma unroll
    for (int kh = 0; kh < 2; ++kh) {
      bfx8 af[2], bfr[4];
#pragma unroll
      for (int mi = 0; mi < 2; ++mi) {
        const int row = wm * 32 + mi * 16 + l15;
        af[mi] = *(const bfx8*)(S + off + row * 128 + ((((kh << 2) + l4) ^ (row & 7)) << 4));
      }
#pragma unroll
      for (int ni = 0; ni < 4; ++ni) {
        const int row = wn * 64 + ni * 16 + l15;
        bfr[ni] = *(const bfx8*)(S + off + 8192 + row * 128 + ((((kh << 2) + l4) ^ (row & 7)) << 4));
      }
#pragma unroll
      for (int mi = 0; mi < 2; ++mi)
#pragma unroll
        for (int ni = 0; ni < 4; ++ni)
          acc[mi][ni] = __builtin_amdgcn_mfma_f32_16x16x32_bf16(af[mi], bfr[ni], acc[mi][ni], 0, 0, 0);
    }
  };

  stage2(0, 0);
  for (int cc = 0; cc < 7; ++cc) {
    const int c0 = cc * 2;
    stage2(c0 + 1, 24576);
    asm volatile("s_waitcnt vmcnt(6)" ::: "memory");
    __builtin_amdgcn_s_barrier();
    __builtin_amdgcn_sched_barrier(0);
    compute2(0);
    __builtin_amdgcn_s_barrier();
    stage2((c0 + 2 < 14) ? c0 + 2 : 13, 0);
    asm volatile("s_waitcnt vmcnt(6)" ::: "memory");
    __builtin_amdgcn_s_barrier();
    __builtin_amdgcn_sched_barrier(0);
    compute2(24576);
    __builtin_amdgcn_s_barrier();
  }
  asm volatile("s_waitcnt vmcnt(0)" ::: "memory");
  float* out = P + (size_t)(mt * SPLITS + sp) * 8192;
#pragma unroll
  for (int mi = 0; mi < 2; ++mi)
#pragma unroll
    for (int ni = 0; ni < 4; ++ni)
#pragma unroll
      for (int i = 0; i < 4; ++i)
        out[(wm * 32 + mi * 16 + l4 * 4 + i) * 128 + wn * 64 + ni * 16 + l15] = acc[mi][ni][i];
}

// ---------------------------------------------------------------------------
// reduce: sum 28 K-split partials + bias, scatter into the two outputs.
// ---------------------------------------------------------------------------
__global__ __launch_bounds__(128) void k_reduce(const float* __restrict__ P,
                                                const float* __restrict__ bc,
                                                float* __restrict__ out) {
  const int m = blockIdx.x;     // 0..1999
  const int c = threadIdx.x;    // 0..127
  if (c >= 105) return;
  const int mt = m >> 6, r = m & 63;
  float sum = 0.0f;
#pragma unroll
  for (int s = 0; s < SPLITS; ++s)
    sum += P[(size_t)(mt * SPLITS + s) * 8192 + r * 128 + c];
  sum += bc[c];
  if (c < 84) out[m * 84 + c] = sum;
  else        out[168000 + m * 21 + (c - 84)] = sum;
}

// ---------------------------------------------------------------------------
extern "C" void kernel_launch(void* const* d_in, const int* in_sizes, int n_in,
                              void* d_out, int out_size, void* d_ws, size_t ws_size,
                              hipStream_t stream) {
  const float* F    = (const float*)d_in[0];
  const float* rois = (const float*)d_in[1];
  const int*   ih   = (const int*)d_in[2];
  const int*   iw   = (const int*)d_in[3];
  const float* Wfc  = (const float*)d_in[4];
  const float* bfc  = (const float*)d_in[5];
  const float* Wl   = (const float*)d_in[6];
  const float* bl   = (const float*)d_in[7];
  const float* Ws   = (const float*)d_in[8];
  const float* bs   = (const float*)d_in[9];
  (void)in_sizes; (void)n_in; (void)out_size; (void)ws_size;

  char* ws = (char*)d_ws;
  // ws layout (bytes):
  //   pool  bf16 [2000][25088]      @ 0          (100,352,000)
  //   WcatT bf16 [128][4096]        @ 100352000  (1,048,576)
  //   WcT   bf16 [128][25088]       @ 101400576  (6,422,528)
  //   bc    f32  [128]              @ 107823104  (512)
  //   P     f32  [896][64][128]     @ 107823616  (29,360,128)  total ~137 MB
  unsigned short* Apool = (unsigned short*)(ws);
  unsigned short* WcatT = (unsigned short*)(ws + 100352000);
  unsigned short* WcT   = (unsigned short*)(ws + 101400576);
  float*          bc    = (float*)(ws + 107823104);
  float*          P     = (float*)(ws + 107823616);
  float*          out   = (float*)d_out;

  k_prep  <<<2176, 256, 0, stream>>>(Wl, Ws, bfc, bl, bs, WcatT, bc);
  k_gemm1 <<<G1BLOCKS, 256, 0, stream>>>(Wfc, WcatT, WcT);
  k_pool  <<<NROIS, 256, 0, stream>>>(F, rois, ih, iw, Apool);
  k_gemm2 <<<dim3(32, SPLITS), 256, 0, stream>>>(Apool, WcT, P);
  k_reduce<<<NROIS, 128, 0, stream>>>(P, bc, out);
}

// Round 13
// 310.243 us; speedup vs baseline: 1.1798x; 1.1798x over previous
//
#include <hip/hip_runtime.h>
#include <stdint.h>

// ---------------------------------------------------------------------------
// RoIHead: out = crop_and_resize(feature, rois) @ (W_fc @ [W_loc|W_score])
//                + (b_fc @ [W_loc|W_score] + [b_loc|b_score])
// R13: split the 411MB W_fc consumption:
//  (a) k_cvt  — copy-shaped grid-stride fp32->bf16 (24 waves/CU, 8 loads in
//      flight/wave). Own profile row = direct measurement of max read BW.
//  (b) k_gemm1b — PROVEN gemm2 structure (6-op gll16 groups, vmcnt(6),
//      48KB LDS, 3 blocks/CU) reading the half-size bf16 copy (L3-warm).
// All other kernels are the proven R8/R11 versions verbatim.
// ---------------------------------------------------------------------------

typedef float          f32x4 __attribute__((ext_vector_type(4)));
typedef __bf16         bfx8  __attribute__((ext_vector_type(8)));
typedef __bf16         bfx2  __attribute__((ext_vector_type(2)));

#define KBIG 25088   // 7*7*512
#define NMID 4096    // FC_OUT
#define NROIS 2000
#define SPLITS 28    // gemm2 K-splits
#define PG1STRIDE 3211264  // 128*25088 floats per gemm1 partial

__device__ __forceinline__ void gll16(const void* g, void* l) {
  __builtin_amdgcn_global_load_lds(
      (const __attribute__((address_space(1))) void*)(uintptr_t)(g),
      (__attribute__((address_space(3))) void*)(uintptr_t)(l), 16, 0, 0);
}

// ---------------------------------------------------------------------------
// prep: blocks 0..2047 build WcatT[128][4096] bf16; 2048..2175 compute bc.
// ---------------------------------------------------------------------------
__global__ __launch_bounds__(256) void k_prep(const float* __restrict__ Wl,
                                              const float* __restrict__ Ws,
                                              const float* __restrict__ bfc,
                                              const float* __restrict__ bl,
                                              const float* __restrict__ bs,
                                              unsigned short* __restrict__ WcatT,
                                              float* __restrict__ bc) {
  if (blockIdx.x < 2048) {
    int idx = blockIdx.x * 256 + threadIdx.x;
    int c = idx >> 12, k = idx & 4095;
    float v = 0.0f;
    if (c < 84)       v = Wl[k * 84 + c];
    else if (c < 105) v = Ws[k * 21 + (c - 84)];
    ((__bf16*)WcatT)[idx] = (__bf16)v;
  } else {
    int c = blockIdx.x - 2048;   // 0..127
    int t = threadIdx.x;
    __shared__ float red[256];
    float p = 0.0f;
    if (c < 105) {
      for (int k = t; k < 4096; k += 256) {
        float w = (c < 84) ? Wl[k * 84 + c] : Ws[k * 21 + (c - 84)];
        p += bfc[k] * w;
      }
    }
    red[t] = p;
    __syncthreads();
    for (int s = 128; s > 0; s >>= 1) {
      if (t < s) red[t] += red[t + s];
      __syncthreads();
    }
    if (t == 0) {
      float bias = (c < 84) ? bl[c] : (c < 105 ? bs[c - 84] : 0.0f);
      bc[c] = (c < 105) ? (red[0] + bias) : 0.0f;
    }
  }
}

// ---------------------------------------------------------------------------
// cvt: W_fc fp32 -> WfcB bf16, copy-shaped. 1568 blocks x 256 threads,
// 8 sub-streams of 3,211,264 elements each; per outer iter a thread issues
// 8 independent 16B loads (8 x 1KB wave-instrs in flight) before 4 stores.
// 8 outer iters cover all 102,760,448 elements exactly.
// ---------------------------------------------------------------------------
__global__ __launch_bounds__(256) void k_cvt(const float* __restrict__ in,
                                             unsigned short* __restrict__ outp) {
  __bf16* out = (__bf16*)outp;
  const size_t S = 3211264;   // elements per sub-sweep
  size_t i = ((size_t)blockIdx.x * 256 + threadIdx.x) * 8;
#pragma unroll 1
  for (int o = 0; o < 8; ++o) {
    f32x4 a0 = *(const f32x4*)(in + i);
    f32x4 a1 = *(const f32x4*)(in + i + 4);
    f32x4 b0 = *(const f32x4*)(in + i + S);
    f32x4 b1 = *(const f32x4*)(in + i + S + 4);
    f32x4 c0 = *(const f32x4*)(in + i + 2 * S);
    f32x4 c1 = *(const f32x4*)(in + i + 2 * S + 4);
    f32x4 d0 = *(const f32x4*)(in + i + 3 * S);
    f32x4 d1 = *(const f32x4*)(in + i + 3 * S + 4);
    bfx8 oa, ob, oc, od;
#pragma unroll
    for (int j = 0; j < 4; ++j) {
      oa[j] = (__bf16)a0[j]; oa[j + 4] = (__bf16)a1[j];
      ob[j] = (__bf16)b0[j]; ob[j + 4] = (__bf16)b1[j];
      oc[j] = (__bf16)c0[j]; oc[j + 4] = (__bf16)c1[j];
      od[j] = (__bf16)d0[j]; od[j + 4] = (__bf16)d1[j];
    }
    *(bfx8*)(out + i)         = oa;
    *(bfx8*)(out + i + S)     = ob;
    *(bfx8*)(out + i + 2 * S) = oc;
    *(bfx8*)(out + i + 3 * S) = od;
    i += 4 * S;
  }
}

// ---------------------------------------------------------------------------
// GEMM1b: Pg1[sp][n][m] f32 = (WfcB[m-tile][k-slice] @ WcatT^T)^T.
// Exact k_gemm2 structure: grid (392 mt, 2 sp), 48KB LDS, 6-op gll16 stage
// groups, counted vmcnt(6), 32 K-steps of BK=64 over the 2048-wide slice.
// ---------------------------------------------------------------------------
__global__ __launch_bounds__(256) void k_gemm1b(const unsigned short* __restrict__ WfcB,
                                                const unsigned short* __restrict__ WcatT,
                                                float* __restrict__ Pg1) {
  __shared__ __align__(16) char S[49152];
  const int t = threadIdx.x;
  const int lane = t & 63, wid = t >> 6;
  const int wm = wid >> 1, wn = wid & 1;
  const int l15 = lane & 15, l4 = lane >> 4;
  const int mt = blockIdx.x, sp = blockIdx.y;
  const int m0 = mt * 64;
  const int kbase = sp * 2048;
  const int jlog = (t & 7) ^ ((t >> 3) & 7);
  f32x4 acc[2][4] = {};

  const unsigned short* asrc0 = WfcB + (size_t)(m0 + (t >> 3)) * NMID + jlog * 8;
  const unsigned short* asrc1 = asrc0 + (size_t)32 * NMID;

  auto stage2 = [&](int c, int off) {
    const int k0 = kbase + c * 64;
    gll16(asrc0 + k0, S + off + wid * 1024);
    gll16(asrc1 + k0, S + off + 4096 + wid * 1024);
#pragma unroll
    for (int q = 0; q < 4; ++q)
      gll16(WcatT + (size_t)(q * 32 + (t >> 3)) * NMID + k0 + jlog * 8,
            S + off + 8192 + q * 4096 + wid * 1024);
  };
  auto compute2 = [&](int off) {
#pragma unroll
    for (int kh = 0; kh < 2; ++kh) {
      bfx8 af[2], bfr[4];
#pragma unroll
      for (int mi = 0; mi < 2; ++mi) {
        const int row = wm * 32 + mi * 16 + l15;
        af[mi] = *(const bfx8*)(S + off + row * 128 + ((((kh << 2) + l4) ^ (row & 7)) << 4));
      }
#pragma unroll
      for (int ni = 0; ni < 4; ++ni) {
        const int row = wn * 64 + ni * 16 + l15;
        bfr[ni] = *(const bfx8*)(S + off + 8192 + row * 128 + ((((kh << 2) + l4) ^ (row & 7)) << 4));
      }
#pragma unroll
      for (int mi = 0; mi < 2; ++mi)
#pragma unroll
        for (int ni = 0; ni < 4; ++ni)
          acc[mi][ni] = __builtin_amdgcn_mfma_f32_16x16x32_bf16(af[mi], bfr[ni], acc[mi][ni], 0, 0, 0);
    }
  };

  stage2(0, 0);
  for (int cc = 0; cc < 16; ++cc) {
    const int c0 = cc * 2;
    stage2(c0 + 1, 24576);
    asm volatile("s_waitcnt vmcnt(6)" ::: "memory");
    __builtin_amdgcn_s_barrier();
    __builtin_amdgcn_sched_barrier(0);
    compute2(0);
    __builtin_amdgcn_s_barrier();
    stage2((c0 + 2 < 32) ? c0 + 2 : 31, 0);
    asm volatile("s_waitcnt vmcnt(6)" ::: "memory");
    __builtin_amdgcn_s_barrier();
    __builtin_amdgcn_sched_barrier(0);
    compute2(24576);
    __builtin_amdgcn_s_barrier();
  }
  asm volatile("s_waitcnt vmcnt(0)" ::: "memory");
  // epilogue: D col(l15)=n, row(l4*4+i)=m -> 16B f32 m-contiguous stores
  float* base = Pg1 + (size_t)sp * PG1STRIDE;
#pragma unroll
  for (int mi = 0; mi < 2; ++mi)
#pragma unroll
    for (int ni = 0; ni < 4; ++ni) {
      const int n = wn * 64 + ni * 16 + l15;
      const int m = m0 + wm * 32 + mi * 16 + l4 * 4;
      *(f32x4*)(base + (size_t)n * KBIG + m) = acc[mi][ni];
    }
}

// ---------------------------------------------------------------------------
// addcvt: WcT[n][m] bf16 = Pg1[0][n][m] + Pg1[1][n][m]
// ---------------------------------------------------------------------------
__global__ __launch_bounds__(256) void k_addcvt(const float* __restrict__ Pg1,
                                                unsigned short* __restrict__ WcT) {
  const size_t i = ((size_t)blockIdx.x * 256 + threadIdx.x) * 8;  // < 128*25088
  f32x4 a0 = *(const f32x4*)(Pg1 + i);
  f32x4 a1 = *(const f32x4*)(Pg1 + i + 4);
  f32x4 b0 = *(const f32x4*)(Pg1 + PG1STRIDE + i);
  f32x4 b1 = *(const f32x4*)(Pg1 + PG1STRIDE + i + 4);
  bfx8 o;
#pragma unroll
  for (int j = 0; j < 4; ++j) {
    o[j]     = (__bf16)(a0[j] + b0[j]);
    o[j + 4] = (__bf16)(a1[j] + b1[j]);
  }
  *(bfx8*)(WcT + i) = o;
}

// ---------------------------------------------------------------------------
// pool: standalone, one block per roi, tf crop_and_resize -> bf16 rows.
// ---------------------------------------------------------------------------
__global__ __launch_bounds__(256) void k_pool(const float* __restrict__ F,
                                              const float* __restrict__ rois,
                                              const int* __restrict__ ihp,
                                              const int* __restrict__ iwp,
                                              unsigned short* __restrict__ A) {
  const int r = blockIdx.x;
  const int t = threadIdx.x;
  const float ih = (float)ihp[0], iw = (float)iwp[0];
  const float y1 = rois[r * 4 + 0] / ih;
  const float x1 = rois[r * 4 + 1] / iw;
  const float y2 = rois[r * 4 + 2] / ih;
  const float x2 = rois[r * 4 + 3] / iw;
  const float sy = (y2 - y1) * 49.0f / 6.0f;
  const float sx = (x2 - x1) * 49.0f / 6.0f;
  const int ch = t * 2;
  __bf16* __restrict__ Arow = (__bf16*)(A + (size_t)r * KBIG);

  auto cellcoords = [&](int cell, int& o00, int& o01, int& o10, int& o11,
                        float& yl, float& xl, bool& valid) {
    const int iy = cell / 7, ix = cell - iy * 7;
    const float in_y = y1 * 49.0f + (float)iy * sy;
    const float in_x = x1 * 49.0f + (float)ix * sx;
    const float y0f = floorf(in_y), x0f = floorf(in_x);
    yl = in_y - y0f; xl = in_x - x0f;
    const int y0  = (int)fminf(fmaxf(y0f, 0.0f), 49.0f);
    const int y1i = (int)fminf(fmaxf(y0f + 1.0f, 0.0f), 49.0f);
    const int x0  = (int)fminf(fmaxf(x0f, 0.0f), 49.0f);
    const int x1i = (int)fminf(fmaxf(x0f + 1.0f, 0.0f), 49.0f);
    valid = (in_y >= 0.0f) && (in_y <= 49.0f) && (in_x >= 0.0f) && (in_x <= 49.0f);
    o00 = (y0 * 50 + x0) * 512;  o01 = (y0 * 50 + x1i) * 512;
    o10 = (y1i * 50 + x0) * 512; o11 = (y1i * 50 + x1i) * 512;
  };

  int o00, o01, o10, o11; float yl, xl; bool valid;
  cellcoords(0, o00, o01, o10, o11, yl, xl, valid);
  float2 f00 = *(const float2*)&F[o00 + ch];
  float2 f01 = *(const float2*)&F[o01 + ch];
  float2 f10 = *(const float2*)&F[o10 + ch];
  float2 f11 = *(const float2*)&F[o11 + ch];

  for (int cell = 0; cell < 49; ++cell) {
    const float2 g00 = f00, g01 = f01, g10 = f10, g11 = f11;
    const float pyl = yl, pxl = xl;
    const bool pv = valid;
    if (cell < 48) {
      cellcoords(cell + 1, o00, o01, o10, o11, yl, xl, valid);
      f00 = *(const float2*)&F[o00 + ch];
      f01 = *(const float2*)&F[o01 + ch];
      f10 = *(const float2*)&F[o10 + ch];
      f11 = *(const float2*)&F[o11 + ch];
    }
    float oA = 0.0f, oB = 0.0f;
    if (pv) {
      float t0 = g00.x * (1.0f - pxl) + g01.x * pxl;
      float t1 = g00.y * (1.0f - pxl) + g01.y * pxl;
      float b0 = g10.x * (1.0f - pxl) + g11.x * pxl;
      float b1 = g10.y * (1.0f - pxl) + g11.y * pxl;
      oA = t0 * (1.0f - pyl) + b0 * pyl;
      oB = t1 * (1.0f - pyl) + b1 * pyl;
    }
    bfx2 v; v[0] = (__bf16)oA; v[1] = (__bf16)oB;
    *(bfx2*)(Arow + cell * 512 + ch) = v;
  }
}

// ---------------------------------------------------------------------------
// GEMM2: P[mt*28+sp][64][128] f32 = pool_tile(mt) @ WcT_slice(sp). (proven)
// ---------------------------------------------------------------------------
__global__ __launch_bounds__(256) void k_gemm2(const unsigned short* __restrict__ Ap,
                                               const unsigned short* __restrict__ WcT,
                                               float* __restrict__ P) {
  __shared__ __align__(16) char S[49152];
  const int t = threadIdx.x;
  const int lane = t & 63, wid = t >> 6;
  const int wm = wid >> 1, wn = wid & 1;
  const int l15 = lane & 15, l4 = lane >> 4;
  const int mt = blockIdx.x, sp = blockIdx.y;
  const int kbase = sp * 896;     // 14 BK-steps of 64
  const int jlog = (t & 7) ^ ((t >> 3) & 7);
  f32x4 acc[2][4] = {};

  int ar0 = mt * 64 + (t >> 3);
  int ar1 = ar0 + 32;
  if (ar0 > NROIS - 1) ar0 = NROIS - 1;
  if (ar1 > NROIS - 1) ar1 = NROIS - 1;
  const unsigned short* asrc0 = Ap + (size_t)ar0 * KBIG + jlog * 8;
  const unsigned short* asrc1 = Ap + (size_t)ar1 * KBIG + jlog * 8;

  auto stage2 = [&](int c, int off) {
    const int k0 = kbase + c * 64;
    gll16(asrc0 + k0, S + off + wid * 1024);
    gll16(asrc1 + k0, S + off + 4096 + wid * 1024);
#pragma unroll
    for (int q = 0; q < 4; ++q)
      gll16(WcT + (size_t)(q * 32 + (t >> 3)) * KBIG + k0 + jlog * 8,
            S + off + 8192 + q * 4096 + wid * 1024);
  };
  auto compute2 = [&](int off) {
#pragma unroll
    for (int kh = 0; kh < 2; ++kh) {
      bfx8 af[2], bfr[4];
#pragma unroll
      for (int mi = 0; mi < 2; ++mi) {
        const int row = wm * 32 + mi * 16 + l15;
        af[mi] = *(const bfx8*)(S + off + row * 128 + ((((kh << 2) + l4) ^ (row & 7)) << 4));
      }
#pragma unroll
      for (int ni = 0; ni < 4; ++ni) {
        const int row = wn * 64 + ni * 16 + l15;
        bfr[ni] = *(const bfx8*)(S + off + 8192 + row * 128 + ((((kh << 2) + l4) ^ (row & 7)) << 4));
      }
#pragma unroll
      for (int mi = 0; mi < 2; ++mi)
#pragma unroll
        for (int ni = 0; ni < 4; ++ni)
          acc[mi][ni] = __builtin_amdgcn_mfma_f32_16x16x32_bf16(af[mi], bfr[ni], acc[mi][ni], 0, 0, 0);
    }
  };

  stage2(0, 0);
  for (int cc = 0; cc < 7; ++cc) {
    const int c0 = cc * 2;
    stage2(c0 + 1, 24576);
    asm volatile("s_waitcnt vmcnt(6)" ::: "memory");
    __builtin_amdgcn_s_barrier();
    __builtin_amdgcn_sched_barrier(0);
    compute2(0);
    __builtin_amdgcn_s_barrier();
    stage2((c0 + 2 < 14) ? c0 + 2 : 13, 0);
    asm volatile("s_waitcnt vmcnt(6)" ::: "memory");
    __builtin_amdgcn_s_barrier();
    __builtin_amdgcn_sched_barrier(0);
    compute2(24576);
    __builtin_amdgcn_s_barrier();
  }
  asm volatile("s_waitcnt vmcnt(0)" ::: "memory");
  float* out = P + (size_t)(mt * SPLITS + sp) * 8192;
#pragma unroll
  for (int mi = 0; mi < 2; ++mi)
#pragma unroll
    for (int ni = 0; ni < 4; ++ni)
#pragma unroll
      for (int i = 0; i < 4; ++i)
        out[(wm * 32 + mi * 16 + l4 * 4 + i) * 128 + wn * 64 + ni * 16 + l15] = acc[mi][ni][i];
}

// ---------------------------------------------------------------------------
// reduce: sum 28 K-split partials + bias, scatter into the two outputs.
// ---------------------------------------------------------------------------
__global__ __launch_bounds__(128) void k_reduce(const float* __restrict__ P,
                                                const float* __restrict__ bc,
                                                float* __restrict__ out) {
  const int m = blockIdx.x;     // 0..1999
  const int c = threadIdx.x;    // 0..127
  if (c >= 105) return;
  const int mt = m >> 6, r = m & 63;
  float sum = 0.0f;
#pragma unroll
  for (int s = 0; s < SPLITS; ++s)
    sum += P[(size_t)(mt * SPLITS + s) * 8192 + r * 128 + c];
  sum += bc[c];
  if (c < 84) out[m * 84 + c] = sum;
  else        out[168000 + m * 21 + (c - 84)] = sum;
}

// ---------------------------------------------------------------------------
extern "C" void kernel_launch(void* const* d_in, const int* in_sizes, int n_in,
                              void* d_out, int out_size, void* d_ws, size_t ws_size,
                              hipStream_t stream) {
  const float* F    = (const float*)d_in[0];
  const float* rois = (const float*)d_in[1];
  const int*   ih   = (const int*)d_in[2];
  const int*   iw   = (const int*)d_in[3];
  const float* Wfc  = (const float*)d_in[4];
  const float* bfc  = (const float*)d_in[5];
  const float* Wl   = (const float*)d_in[6];
  const float* bl   = (const float*)d_in[7];
  const float* Ws   = (const float*)d_in[8];
  const float* bs   = (const float*)d_in[9];
  (void)in_sizes; (void)n_in; (void)out_size; (void)ws_size;

  char* ws = (char*)d_ws;
  // ws layout (bytes):
  //   pool  bf16 [2000][25088]      @ 0          (100,352,000)
  //   WcatT bf16 [128][4096]        @ 100352000  (1,048,576)
  //   WcT   bf16 [128][25088]       @ 101400576  (6,422,528)
  //   bc    f32  [128]              @ 107823104  (512)
  //   P     f32  [896][64][128]     @ 107823616  (29,360,128)
  //   Pg1   f32  [2][128][25088]    @ 137183744  (25,690,112)
  //   WfcB  bf16 [25088][4096]      @ 162873856  (205,520,896)  total ~368 MB
  unsigned short* Apool = (unsigned short*)(ws);
  unsigned short* WcatT = (unsigned short*)(ws + 100352000);
  unsigned short* WcT   = (unsigned short*)(ws + 101400576);
  float*          bc    = (float*)(ws + 107823104);
  float*          P     = (float*)(ws + 107823616);
  float*          Pg1   = (float*)(ws + 137183744);
  unsigned short* WfcB  = (unsigned short*)(ws + 162873856);
  float*          out   = (float*)d_out;

  k_prep  <<<2176, 256, 0, stream>>>(Wl, Ws, bfc, bl, bs, WcatT, bc);
  k_cvt   <<<1568, 256, 0, stream>>>(Wfc, WfcB);
  k_gemm1b<<<dim3(392, 2), 256, 0, stream>>>(WfcB, WcatT, Pg1);   // WfcB L3-warm
  k_addcvt<<<1568, 256, 0, stream>>>(Pg1, WcT);
  k_pool  <<<NROIS, 256, 0, stream>>>(F, rois, ih, iw, Apool);
  k_gemm2 <<<dim3(32, SPLITS), 256, 0, stream>>>(Apool, WcT, P);
  k_reduce<<<NROIS, 128, 0, stream>>>(P, bc, out);
}